// Round 1
// baseline (3254.339 us; speedup 1.0000x reference)
//
#include <hip/hip_runtime.h>
#include <stdint.h>

// Problem dims
#define TS  256
#define CTS 512
#define BB  64
#define HH  512
#define KK  10

typedef short short8 __attribute__((ext_vector_type(8)));
typedef float floatx4 __attribute__((ext_vector_type(4)));

__device__ __forceinline__ unsigned short f2bf(float f) {
  unsigned u = __float_as_uint(f);
  unsigned r = (u + 0x7fffu + ((u >> 16) & 1u)) >> 16;  // RNE
  return (unsigned short)r;
}

// ---------------------------------------------------------------------------
// K1: Wcat [2048][1024] bf16.
// Row groups of 512: g0 = r-gate [W_hh_r | W_ih_r]; g1 = z-gate [W_hh_z | W_ih_z];
// g2 = i_n [0 | W_ih_n]; g3 = h_n [W_hh_n | 0]. (n-gate split because n = tanh(i_n + r*h_n))
__global__ void k_wcat(const float* __restrict__ W_ih, const float* __restrict__ W_hh,
                       unsigned short* __restrict__ Wcat) {
  int idx = blockIdx.x * 256 + threadIdx.x;  // 2048*1024 total
  int r = idx >> 10, c = idx & 1023;
  int g = r >> 9, j = r & 511;
  float v;
  if (g == 0)      v = (c < 512) ? W_hh[j * 512 + c]          : W_ih[j * 512 + (c - 512)];
  else if (g == 1) v = (c < 512) ? W_hh[(512 + j) * 512 + c]  : W_ih[(512 + j) * 512 + (c - 512)];
  else if (g == 2) v = (c < 512) ? 0.f                        : W_ih[(1024 + j) * 512 + (c - 512)];
  else             v = (c < 512) ? W_hh[(1024 + j) * 512 + c] : 0.f;
  Wcat[idx] = f2bf(v);
}

// ---------------------------------------------------------------------------
// K2: G[t*64+b][30] = exp(x_t[b] @ {Wa;Wb;Wk}.T + bias). One wave per (t,b) row.
__global__ void k_abk(const float* __restrict__ inp,
                      const float* __restrict__ Wa, const float* __restrict__ ba,
                      const float* __restrict__ Wb, const float* __restrict__ bvb,
                      const float* __restrict__ Wk, const float* __restrict__ bk,
                      float* __restrict__ G) {
  int row = blockIdx.x;                 // t*64 + b
  int lane = threadIdx.x;               // 0..63
  int j = lane & 31, half = lane >> 5;  // j = output idx, half = K-half
  const float* Wrow; float bias;
  if (j < 10)      { Wrow = Wa + j * 512;        bias = ba[j]; }
  else if (j < 20) { Wrow = Wb + (j - 10) * 512; bias = bvb[j - 10]; }
  else if (j < 30) { Wrow = Wk + (j - 20) * 512; bias = bk[j - 20]; }
  else             { Wrow = Wa;                  bias = 0.f; }
  const float4* x4 = (const float4*)(inp + row * 512 + half * 256);
  const float4* w4 = (const float4*)(Wrow + half * 256);
  float acc = 0.f;
#pragma unroll 8
  for (int i = 0; i < 64; ++i) {
    float4 a = x4[i], w = w4[i];
    acc += a.x * w.x + a.y * w.y + a.z * w.z + a.w * w.w;
  }
  acc += __shfl_down(acc, 32, 64);  // fold the two K-halves
  if (lane < 30) G[row * 30 + lane] = __expf(acc + bias);
}

// ---------------------------------------------------------------------------
// K3: k_t cumsum over t for each (b,k). Writes att_k output (fp32).
__global__ void k_cumsum(const float* __restrict__ G, const float* __restrict__ att_init,
                         float* __restrict__ out_k) {
  int gid = blockIdx.x * 64 + threadIdx.x;
  if (gid >= BB * KK) return;
  int b = gid / KK, k = gid - b * KK;
  float acc = att_init[b * KK + k];
  for (int t = 0; t < TS; ++t) {
    acc += G[(t * BB + b) * 30 + 20 + k];
    out_k[(t * BB + b) * KK + k] = acc;
  }
}

// ---------------------------------------------------------------------------
// K4: phi[b][t][s] = sum_k a*exp(-b*(k_t - s)^2), stored bf16 (A-matrix of att_w GEMM).
__global__ void k_phi(const float* __restrict__ G, const float* __restrict__ attk,
                      unsigned short* __restrict__ phi_bf) {
  int t = blockIdx.x, b = blockIdx.y;
  int row = t * BB + b;
  float a[10], bv[10], kt[10];
#pragma unroll
  for (int k = 0; k < 10; ++k) {
    a[k]  = G[row * 30 + k];
    bv[k] = G[row * 30 + 10 + k];
    kt[k] = attk[row * KK + k];
  }
#pragma unroll
  for (int e = 0; e < 2; ++e) {
    int s = threadIdx.x + e * 256;
    float fs = (float)s;
    float ph = 0.f;
#pragma unroll
    for (int k = 0; k < 10; ++k) {
      float d = kt[k] - fs;
      ph += a[k] * __expf(-bv[k] * d * d);
    }
    phi_bf[(b * TS + t) * CTS + s] = f2bf(ph);
  }
}

// ---------------------------------------------------------------------------
// K5: att_w[t][b][h] = sum_s phi[b][t][s] * c_inp[s][b][h].
// Per-b GEMM [256x512]@[512x512], MFMA 16x16x32 bf16. Block = (h-tile 64, t-tile 64, b).
// B-tile (c_inp slice, s-strided) staged+transposed through LDS with bf16 convert.
__global__ __launch_bounds__(256) void k_attw(
    const float* __restrict__ c_inp, const unsigned short* __restrict__ phi_bf,
    float* __restrict__ out_w, unsigned short* __restrict__ attw_bf) {
  int h0 = blockIdx.x * 64;
  int t0 = blockIdx.y * 64;
  int b  = blockIdx.z;
  int tid = threadIdx.x;
  int lane = tid & 63, wv = tid >> 6;
  int x = lane & 15, q = lane >> 4;
  __shared__ __align__(16) unsigned short Bt[64 * 40];  // [h_local][s_local], stride 40 (pad)
  floatx4 acc[4];
#pragma unroll
  for (int m = 0; m < 4; ++m) acc[m] = (floatx4){0.f, 0.f, 0.f, 0.f};
  int s_l = tid >> 3, h8 = (tid & 7) * 8;
  for (int ss = 0; ss < 16; ++ss) {
    int s0 = ss * 32;
    const float* src = c_inp + ((s0 + s_l) * BB + b) * HH + h0 + h8;
    float4 v0 = *(const float4*)src;
    float4 v1 = *(const float4*)(src + 4);
    Bt[(h8 + 0) * 40 + s_l] = f2bf(v0.x);
    Bt[(h8 + 1) * 40 + s_l] = f2bf(v0.y);
    Bt[(h8 + 2) * 40 + s_l] = f2bf(v0.z);
    Bt[(h8 + 3) * 40 + s_l] = f2bf(v0.w);
    Bt[(h8 + 4) * 40 + s_l] = f2bf(v1.x);
    Bt[(h8 + 5) * 40 + s_l] = f2bf(v1.y);
    Bt[(h8 + 6) * 40 + s_l] = f2bf(v1.z);
    Bt[(h8 + 7) * 40 + s_l] = f2bf(v1.w);
    __syncthreads();
    short8 bfrag = *(const short8*)(Bt + (wv * 16 + x) * 40 + q * 8);
#pragma unroll
    for (int mt = 0; mt < 4; ++mt) {
      short8 af = *(const short8*)(phi_bf + (b * TS + t0 + mt * 16 + x) * CTS + s0 + q * 8);
      acc[mt] = __builtin_amdgcn_mfma_f32_16x16x32_bf16(af, bfrag, acc[mt], 0, 0, 0);
    }
    __syncthreads();
  }
#pragma unroll
  for (int mt = 0; mt < 4; ++mt)
#pragma unroll
    for (int r = 0; r < 4; ++r) {
      int t_l = mt * 16 + q * 4 + r;           // C/D: row = quad*4+reg
      int row = (t0 + t_l) * BB + b;
      int col = h0 + wv * 16 + x;              // C/D: col = lane&15
      float v = acc[mt][r];
      out_w[row * HH + col] = v;
      attw_bf[row * HH + col] = f2bf(v);
    }
}

// ---------------------------------------------------------------------------
// K6: persistent sequential GRU. 64 WGs (cooperative), WG w owns h-dims [w*8, w*8+8).
// Weights (32 rows x 1024 K) live in 128 VGPRs per thread (B-fragments), preloaded once.
// Per step: gh' = [h_{t-1} | w_t] @ Wcat_slice.T via MFMA; gates; publish h bf16 via
// agent-scope atomics; flag barrier (padded flags, lane-parallel poll).
__global__ __launch_bounds__(256, 1) void k_seq(
    const unsigned short* __restrict__ attw_bf, const unsigned short* __restrict__ Wcat,
    const float* __restrict__ gru_init, const float* __restrict__ b_ih,
    const float* __restrict__ b_hh,
    unsigned short* __restrict__ h_buf, unsigned* __restrict__ flags,
    float* __restrict__ hid_out) {
  const int w = blockIdx.x, j0 = w * 8;
  const int tid = threadIdx.x;
  const int lane = tid & 63, wv = tid >> 6;
  const int x = lane & 15, q = lane >> 4;
  const int mpair = wv >> 1;   // which pair of 16-batch M-tiles
  const int khalf = wv & 1;    // 0: K 0..511 (h part), 1: K 512..1023 (w part)

  __shared__ float gbuf[2 * 64 * 33];  // [khalf][b][n(32)] partial pre-activations
  __shared__ float bsum[32];           // folded biases per n-col

  // Preload weight B-fragments into registers (time-invariant).
  short8 wfrag[2][16];
#pragma unroll
  for (int nt = 0; nt < 2; ++nt) {
    int nl = nt * 16 + x;
    int grow = (nl >> 3) * 512 + j0 + (nl & 7);  // group*512 + j
#pragma unroll
    for (int kk = 0; kk < 16; ++kk)
      wfrag[nt][kk] = *(const short8*)(Wcat + grow * 1024 + (khalf * 16 + kk) * 32 + q * 8);
  }
  if (tid < 32) {
    int g = tid >> 3, jl = tid & 7, j = j0 + jl;
    float v;
    if (g == 0)      v = b_ih[j] + b_hh[j];
    else if (g == 1) v = b_ih[512 + j] + b_hh[512 + j];
    else if (g == 2) v = b_ih[1024 + j];
    else             v = b_hh[1024 + j];
    bsum[tid] = v;
  }

  // Each thread owns 2 consecutive (b, jl) cells of this WG's h-slice.
  int p0 = tid * 2;
  int bo = p0 >> 3, jl0 = p0 & 7;  // jl0 even
  float hp0 = gru_init[bo * HH + j0 + jl0];
  float hp1 = gru_init[bo * HH + j0 + jl0 + 1];
  {
    unsigned pk = (unsigned)f2bf(hp0) | ((unsigned)f2bf(hp1) << 16);
    __hip_atomic_store((unsigned*)(h_buf + bo * HH + j0 + jl0), pk,
                       __ATOMIC_RELAXED, __HIP_MEMORY_SCOPE_AGENT);
  }
  __builtin_amdgcn_s_waitcnt(0);  // drain this wave's stores (write-through, agent scope)
  __syncthreads();
  if (tid == 0)
    __hip_atomic_store(&flags[w * 32], 1u, __ATOMIC_RELEASE, __HIP_MEMORY_SCOPE_AGENT);

  for (int t = 0; t < TS; ++t) {
    // Barrier: wait until every WG has published h_{t-1} (flag >= t+1).
    if (tid < 64) {
      while (__hip_atomic_load(&flags[tid * 32], __ATOMIC_RELAXED,
                               __HIP_MEMORY_SCOPE_AGENT) < (unsigned)(t + 1)) {}
    }
    __syncthreads();
    const unsigned short* hsrc = h_buf + (t & 1) * (BB * HH);
    unsigned short* hdst = h_buf + ((t + 1) & 1) * (BB * HH);

    floatx4 acc[2][2];
#pragma unroll
    for (int m = 0; m < 2; ++m)
#pragma unroll
      for (int nt = 0; nt < 2; ++nt) acc[m][nt] = (floatx4){0.f, 0.f, 0.f, 0.f};

#pragma unroll
    for (int kk = 0; kk < 16; ++kk) {
      short8 af[2];
      if (khalf == 0) {
#pragma unroll
        for (int m = 0; m < 2; ++m) {
          int bb = (mpair * 2 + m) * 16 + x;  // A: m = lane&15
          const unsigned long long* pp =
              (const unsigned long long*)(hsrc + bb * HH + kk * 32 + q * 8);
          unsigned long long lo = __hip_atomic_load(pp, __ATOMIC_RELAXED, __HIP_MEMORY_SCOPE_AGENT);
          unsigned long long hi = __hip_atomic_load(pp + 1, __ATOMIC_RELAXED, __HIP_MEMORY_SCOPE_AGENT);
          union { unsigned long long u[2]; short8 s; } cv;
          cv.u[0] = lo; cv.u[1] = hi;
          af[m] = cv.s;
        }
      } else {
#pragma unroll
        for (int m = 0; m < 2; ++m) {
          int bb = (mpair * 2 + m) * 16 + x;
          af[m] = *(const short8*)(attw_bf + (t * BB + bb) * HH + kk * 32 + q * 8);
        }
      }
#pragma unroll
      for (int nt = 0; nt < 2; ++nt) {
#pragma unroll
        for (int m = 0; m < 2; ++m)
          acc[m][nt] = __builtin_amdgcn_mfma_f32_16x16x32_bf16(af[m], wfrag[nt][kk], acc[m][nt], 0, 0, 0);
      }
    }

    // Scatter D into gbuf for the cross-lane gate combine.
#pragma unroll
    for (int m = 0; m < 2; ++m)
#pragma unroll
      for (int nt = 0; nt < 2; ++nt)
#pragma unroll
        for (int r = 0; r < 4; ++r) {
          int bb = (mpair * 2 + m) * 16 + q * 4 + r;  // C/D: row = quad*4+reg
          gbuf[khalf * (64 * 33) + bb * 33 + nt * 16 + x] = acc[m][nt][r];
        }
    __syncthreads();

    // Gates for this thread's 2 (b, jl) cells.
    {
      const float* g0 = gbuf + bo * 33;
      const float* g1 = gbuf + 64 * 33 + bo * 33;
      float hprev[2] = {hp0, hp1};
      float hnew[2];
#pragma unroll
      for (int e = 0; e < 2; ++e) {
        int jl = jl0 + e;
        float rp = g0[jl]      + g1[jl]      + bsum[jl];
        float zp = g0[8 + jl]  + g1[8 + jl]  + bsum[8 + jl];
        float ip = g0[16 + jl] + g1[16 + jl] + bsum[16 + jl];
        float hn = g0[24 + jl] + g1[24 + jl] + bsum[24 + jl];
        float r_ = 1.f / (1.f + __expf(-rp));
        float z_ = 1.f / (1.f + __expf(-zp));
        float n_ = tanhf(ip + r_ * hn);
        float hv = (1.f - z_) * n_ + z_ * hprev[e];
        hnew[e] = hv;
        hid_out[(t * BB + bo) * HH + j0 + jl] = hv;
      }
      hp0 = hnew[0]; hp1 = hnew[1];
    }
    {
      unsigned pk = (unsigned)f2bf(hp0) | ((unsigned)f2bf(hp1) << 16);
      __hip_atomic_store((unsigned*)(hdst + bo * HH + j0 + jl0), pk,
                         __ATOMIC_RELAXED, __HIP_MEMORY_SCOPE_AGENT);
    }
    __builtin_amdgcn_s_waitcnt(0);
    __syncthreads();  // all h published + gbuf consumed
    if (tid == 0)
      __hip_atomic_store(&flags[w * 32], (unsigned)(t + 2), __ATOMIC_RELEASE, __HIP_MEMORY_SCOPE_AGENT);
  }
}

// ---------------------------------------------------------------------------
extern "C" void kernel_launch(void* const* d_in, const int* in_sizes, int n_in,
                              void* d_out, int out_size, void* d_ws, size_t ws_size,
                              hipStream_t stream) {
  const float* c_inp    = (const float*)d_in[0];
  const float* inp      = (const float*)d_in[1];
  const float* gru_init = (const float*)d_in[2];
  const float* att_init = (const float*)d_in[3];
  const float* Wa = (const float*)d_in[4];
  const float* ba = (const float*)d_in[5];
  const float* Wb = (const float*)d_in[6];
  const float* bvb = (const float*)d_in[7];
  const float* Wk = (const float*)d_in[8];
  const float* bk = (const float*)d_in[9];
  const float* W_ih = (const float*)d_in[10];
  const float* b_ih = (const float*)d_in[11];
  const float* W_hh = (const float*)d_in[12];
  const float* b_hh = (const float*)d_in[13];

  float* out_h = (float*)d_out;                     // hiddens [256,64,512]
  float* out_k = out_h + TS * BB * HH;              // att_k   [256,64,10]
  float* out_w = out_k + TS * BB * KK;              // att_w   [256,64,512]

  char* ws = (char*)d_ws;
  float* G             = (float*)(ws);                              //  7.5 MB
  unsigned short* Wcat = (unsigned short*)(ws + 8388608);           //  4   MB
  unsigned short* phi  = (unsigned short*)(ws + 12582912);          // 16   MB
  unsigned short* awb  = (unsigned short*)(ws + 29360128);          // 16   MB
  unsigned short* hbuf = (unsigned short*)(ws + 46137344);          // 128  KB
  unsigned* flags      = (unsigned*)(ws + 46268416);                //  8   KB

  hipMemsetAsync(flags, 0, 64 * 128, stream);
  hipLaunchKernelGGL(k_wcat, dim3(8192), dim3(256), 0, stream, W_ih, W_hh, Wcat);
  hipLaunchKernelGGL(k_abk, dim3(TS * BB), dim3(64), 0, stream,
                     inp, Wa, ba, Wb, bvb, Wk, bk, G);
  hipLaunchKernelGGL(k_cumsum, dim3(10), dim3(64), 0, stream, G, att_init, out_k);
  hipLaunchKernelGGL(k_phi, dim3(TS, BB), dim3(256), 0, stream, G, out_k, phi);
  hipLaunchKernelGGL(k_attw, dim3(8, 4, BB), dim3(256), 0, stream, c_inp, phi, out_w, awb);

  const unsigned short* a_awb = awb;
  const unsigned short* a_wc = Wcat;
  const float* a_gi = gru_init;
  const float* a_bih = b_ih;
  const float* a_bhh = b_hh;
  unsigned short* a_hb = hbuf;
  unsigned* a_fl = flags;
  float* a_oh = out_h;
  void* args[] = { (void*)&a_awb, (void*)&a_wc, (void*)&a_gi, (void*)&a_bih,
                   (void*)&a_bhh, (void*)&a_hb, (void*)&a_fl, (void*)&a_oh };
  hipLaunchCooperativeKernel((const void*)k_seq, dim3(64), dim3(256), args, 0, stream);
}